// Round 4
// baseline (550.953 us; speedup 1.0000x reference)
//
#include <hip/hip_runtime.h>
#include <hip/hip_bf16.h>

// HopfieldLayer: out = softmax(x @ Wl^T * beta) @ Wc^T
//   x [16384,768] f32, Wl [4096,768] f32, Wc [768,4096] f32 -> out [16384,768] f32
// R7: mfma 32x32x16 (8.07cy/32KFLOP vs 4.85/16K) + 2 phases per K-tile
// (16 MFMA each) -> half the barrier-steps of R1/R6 at same staged bytes.
// Same fragment-ordered LDS (16-row x 32-k subfrags, conflict-free for both
// gload_lds and 32-row ds_read_b128 reads). vmcnt(4) once per tile.

#define NTOK   16384
#define DIM    768
#define NPROT  4096
#define BETA_F 0.03608439182428583f

typedef __bf16 bf16_t;
typedef __bf16 bf16x8 __attribute__((ext_vector_type(8)));
typedef float  floatx16 __attribute__((ext_vector_type(16)));

// ---------------------------------------------------------------- async 16B copy
__device__ __forceinline__ void async_copy16(const bf16_t* g, void* l) {
  __builtin_amdgcn_global_load_lds(
      (__attribute__((address_space(1))) const void*)g,
      (__attribute__((address_space(3))) void*)l, 16, 0, 0);
}

// ---------------------------------------------------------------- f32 -> bf16
__global__ __launch_bounds__(256) void cvt_all(
    const float* __restrict__ x, const float* __restrict__ wl,
    const float* __restrict__ wc, bf16_t* __restrict__ xb,
    bf16_t* __restrict__ wlb, bf16_t* __restrict__ wcb,
    int nx8, int nw8, int nc8) {
  int i = blockIdx.x * 256 + threadIdx.x;
  const float* in; bf16_t* out; int k;
  if (i < nx8)            { in = x;  out = xb;  k = i; }
  else if (i < nx8 + nw8) { in = wl; out = wlb; k = i - nx8; }
  else if (i < nx8 + nw8 + nc8) { in = wc; out = wcb; k = i - nx8 - nw8; }
  else return;
  const float4* in4 = (const float4*)in;
  float4 a = in4[2 * k], b = in4[2 * k + 1];
  bf16x8 o;
  o[0] = (bf16_t)a.x; o[1] = (bf16_t)a.y; o[2] = (bf16_t)a.z; o[3] = (bf16_t)a.w;
  o[4] = (bf16_t)b.x; o[5] = (bf16_t)b.y; o[6] = (bf16_t)b.z; o[7] = (bf16_t)b.w;
  ((bf16x8*)out)[k] = o;
}

// ---------------------------------------------------------------- gemm C = A * B^T
// A: M x K row-major bf16, B: N x K row-major bf16. 256x256 tile, BK=64,
// 8 waves 2(M)x4(N); wave tile 128x64 = 4 Mfrags x 2 Nfrags of 32x32.
// LDS per slot: 32 subfrags of 1KB per operand; subfrag (f16, ks32):
//   rows f16*16..+15, k-bytes ks32*64..+63; entry = (row&15)|(kchunk16<<4).
// Per K-tile: 2 phases (fm pair 0/1), each:
//   { ds_reads (af pair [+bg in q1]) ; stage 1 full half... (A or B both
//     halves, 4 loads) ; BAR ; lgkm0 ; setprio 16 MFMA 32x32x16 ; [VM] ; BAR }
// Ledger: y.q1 stages A(y+1)->slot^1 (dead since (y-1).q2); y.q2 stages
// B(y+2)->slot (dead since y.q1) then VM(4): outstanding {B(y+1),A(y+1),
// B(y+2)} = 12 -> first 8 complete = tile y+1 fully landed.
template <int EPI>
__global__ __launch_bounds__(512, 2)
void gemm256(const bf16_t* __restrict__ A, const bf16_t* __restrict__ B,
             void* __restrict__ Cv, float* __restrict__ rowsum,
             const int K, const int N, const int nN) {
  __shared__ char lds[131072];

  const int tid = threadIdx.x;
  const int l   = tid & 63;
  const int w   = tid >> 6;       // 0..7
  const int wr  = w >> 2;         // 0..1  (M)
  const int wc  = w & 3;          // 0..3  (N)
  const int lr  = l & 15;
  const int lk  = (l >> 4) << 3;  // staging k-offset: 0,8,16,24
  const int l31 = l & 31;
  const int h5  = l >> 5;         // 0..1

  // bijective XCD swizzle (nwg % 8 == 0); n-fast within chunk
  const int nwg   = gridDim.x;
  const int chunk = nwg >> 3;
  const int wg    = (blockIdx.x & 7) * chunk + (blockIdx.x >> 3);
  const int m0    = (wg / nN) * 256;
  const int n0    = (wg % nN) * 256;

  // staging: thread (w,l), j in {0,1} -> subfrag s=j*8+w of a half-tile
  int aoff[2][2], boff[2][2];
#pragma unroll
  for (int h = 0; h < 2; ++h)
#pragma unroll
    for (int j = 0; j < 2; ++j) {
      const int s     = j * 8 + w;
      const int mfrag = h * 8 + (s >> 1);
      const int ks    = s & 1;
      aoff[h][j] = (m0 + mfrag * 16 + lr) * K + ks * 32 + lk;
      boff[h][j] = (n0 + mfrag * 16 + lr) * K + ks * 32 + lk;
    }

  auto stageA32 = [&](int slot, int kt) {  // both halves: 4 loads/thread
#pragma unroll
    for (int h = 0; h < 2; ++h)
#pragma unroll
      for (int j = 0; j < 2; ++j) {
        const int s  = j * 8 + w;
        const int sf = (h * 8 + (s >> 1)) * 2 + (s & 1);
        async_copy16(A + aoff[h][j] + kt * 64, lds + slot * 65536 + sf * 1024);
      }
  };
  auto stageB32 = [&](int slot, int kt) {
#pragma unroll
    for (int h = 0; h < 2; ++h)
#pragma unroll
      for (int j = 0; j < 2; ++j) {
        const int s  = j * 8 + w;
        const int sf = (h * 8 + (s >> 1)) * 2 + (s & 1);
        async_copy16(B + boff[h][j] + kt * 64,
                     lds + slot * 65536 + 32768 + sf * 1024);
      }
  };

  // 32-row fragment reads from the 16-row-subfrag layout:
  // lane: row = base + (l&31); 16B k-chunk c = ks16*2 + (l>>5)
  // addr = slot*65536 [+32768 B] + ((row>>4)*2 + (c>>2))*1024
  //        + ((row&15) + ((c&3)<<4))*16      -- 4x256B contiguous, conflict-free
  auto ldA = [&](int slot, int fm, int ks16) -> bf16x8 {
    const int row = wr * 128 + fm * 32 + l31;
    const int c   = ks16 * 2 + h5;
    return *(const bf16x8*)(lds + slot * 65536 +
               (((row >> 4) * 2 + (c >> 2)) << 10) +
               (((row & 15) + ((c & 3) << 4)) << 4));
  };
  auto ldB = [&](int slot, int fn, int ks16) -> bf16x8 {
    const int row = wc * 64 + fn * 32 + l31;
    const int c   = ks16 * 2 + h5;
    return *(const bf16x8*)(lds + slot * 65536 + 32768 +
               (((row >> 4) * 2 + (c >> 2)) << 10) +
               (((row & 15) + ((c & 3) << 4)) << 4));
  };

  bf16x8 af[2][4], bg[2][4];

  const floatx16 z = {0.f};
  floatx16 acc[4][2];
#pragma unroll
  for (int fm = 0; fm < 4; ++fm)
#pragma unroll
    for (int fn = 0; fn < 2; ++fn) acc[fm][fn] = z;

  auto loadAfPair = [&](int slot, int mq) {  // fm = mq*2, mq*2+1
#pragma unroll
    for (int q = 0; q < 2; ++q)
#pragma unroll
      for (int ks = 0; ks < 4; ++ks) af[q][ks] = ldA(slot, mq * 2 + q, ks);
  };
  auto loadBgAll = [&](int slot) {
#pragma unroll
    for (int fn = 0; fn < 2; ++fn)
#pragma unroll
      for (int ks = 0; ks < 4; ++ks) bg[fn][ks] = ldB(slot, fn, ks);
  };

  auto mma = [&](int mq) {  // 16 MFMA: fm=mq*2+q, fn, ks
    __builtin_amdgcn_s_setprio(1);
#pragma unroll
    for (int q = 0; q < 2; ++q)
#pragma unroll
      for (int fn = 0; fn < 2; ++fn)
#pragma unroll
        for (int ks = 0; ks < 4; ++ks)
          acc[mq * 2 + q][fn] = __builtin_amdgcn_mfma_f32_32x32x16_bf16(
              af[q][ks], bg[fn][ks], acc[mq * 2 + q][fn], 0, 0, 0);
    __builtin_amdgcn_s_setprio(0);
  };

#define BAR()    do { __builtin_amdgcn_s_barrier(); \
                      __builtin_amdgcn_sched_barrier(0); } while (0)
#define LGKM0()  do { asm volatile("s_waitcnt lgkmcnt(0)" ::: "memory"); \
                      __builtin_amdgcn_sched_barrier(0); } while (0)
#define VM(n)    asm volatile("s_waitcnt vmcnt(" #n ")" ::: "memory")

  const int T = K >> 6;  // 12 (K=768) or 64 (K=4096); even, >= 4

  // prologue: tile0 A+B, tile1 B; A1 staged at 0.q1
  stageA32(0, 0); stageB32(0, 0); stageB32(1, 1);  // 12 loads
  VM(4);  // tile0's 8 landed; B1 in flight
  BAR();

#pragma unroll 1
  for (int y = 0; y + 3 < T; y += 2) {
#pragma unroll
    for (int u = 0; u < 2; ++u) {       // tile y+u, slot u
      const int p = u;
      // q1: fm 0,1 ; load bg for the tile ; stage A(y+u+1)
      loadAfPair(p, 0);
      loadBgAll(p);
      stageA32(p ^ 1, y + u + 1);
      BAR(); LGKM0();
      mma(0);
      BAR();
      // q2: fm 2,3 ; stage B(y+u+2) ; VM(4) -> tile y+u+1 landed
      loadAfPair(p, 1);
      stageB32(p, y + u + 2);
      BAR(); LGKM0();
      mma(1);
      VM(4);
      BAR();
    }
  }

  // ---- tail: tile T-2 (slot0), tile T-1 (slot1) ----
  loadAfPair(0, 0);
  loadBgAll(0);
  stageA32(1, T - 1);                   // last stage
  BAR(); LGKM0();
  mma(0);
  BAR();
  loadAfPair(0, 1);
  BAR(); LGKM0();
  mma(1);
  VM(0);                                // A(T-1) landed
  BAR();
  loadAfPair(1, 0);
  loadBgAll(1);
  BAR(); LGKM0();
  mma(0);
  BAR();
  loadAfPair(1, 1);
  BAR(); LGKM0();
  mma(1);

#undef BAR
#undef LGKM0
#undef VM

  // 32x32 C/D layout (m74/m101): col = lane&31, row = (i&3)+8*(i>>2)+4*(lane>>5)
  // frag (fm,fn): row = m0+wr*128+fm*32+rrow, col = n0+wc*64+fn*32+(l&31)
  if (EPI == 0) {
    bf16_t* P = (bf16_t*)Cv;
#pragma unroll
    for (int fm = 0; fm < 4; ++fm) {
      const int rowb = m0 + wr * 128 + fm * 32;
      float rs[16];
#pragma unroll
      for (int i = 0; i < 16; ++i) rs[i] = 0.f;
#pragma unroll
      for (int fn = 0; fn < 2; ++fn) {
        const int col = n0 + wc * 64 + fn * 32 + l31;
#pragma unroll
        for (int i = 0; i < 16; ++i) {
          const float e = __expf(acc[fm][fn][i] * BETA_F);
          const int row = rowb + (i & 3) + 8 * (i >> 2) + 4 * h5;
          P[row * N + col] = (bf16_t)e;
          rs[i] += e;
        }
      }
#pragma unroll
      for (int i = 0; i < 16; ++i) {  // reduce across the 32 col-lanes
        float s = rs[i];
        s += __shfl_xor(s, 1);
        s += __shfl_xor(s, 2);
        s += __shfl_xor(s, 4);
        s += __shfl_xor(s, 8);
        s += __shfl_xor(s, 16);
        if (l31 == 0)
          atomicAdd(&rowsum[rowb + (i & 3) + 8 * (i >> 2) + 4 * h5], s);
      }
    }
  } else {
    float* O = (float*)Cv;
#pragma unroll
    for (int fm = 0; fm < 4; ++fm) {
      const int rowb = m0 + wr * 128 + fm * 32;
#pragma unroll
      for (int i = 0; i < 16; ++i) {
        const int row = rowb + (i & 3) + 8 * (i >> 2) + 4 * h5;
        const float inv = 1.0f / rowsum[row];
#pragma unroll
        for (int fn = 0; fn < 2; ++fn)
          O[row * N + n0 + wc * 64 + fn * 32 + l31] = acc[fm][fn][i] * inv;
      }
    }
  }
}

// ---------------------------------------------------------------- fallback (no ws)
__global__ __launch_bounds__(256) void hopfield_fallback(
    const float* __restrict__ x, const float* __restrict__ wl,
    const float* __restrict__ wc, float* __restrict__ out) {
  __shared__ float  xs[8 * 768];
  __shared__ bf16_t ps[8 * 4096];
  __shared__ float  rs[8];
  const int tid = threadIdx.x;
  const int r0  = blockIdx.x * 8;
  if (tid < 8) rs[tid] = 0.f;
  for (int i = tid; i < 8 * 768; i += 256)
    xs[i] = x[(r0 + (i / 768)) * 768 + (i % 768)];
  __syncthreads();

  float lsum[8] = {0, 0, 0, 0, 0, 0, 0, 0};
  for (int p = tid; p < 4096; p += 256) {
    float s[8] = {0, 0, 0, 0, 0, 0, 0, 0};
    for (int d = 0; d < 768; ++d) {
      const float wv = wl[p * 768 + d];
#pragma unroll
      for (int r = 0; r < 8; ++r) s[r] += xs[r * 768 + d] * wv;
    }
#pragma unroll
    for (int r = 0; r < 8; ++r) {
      const float e = __expf(s[r] * BETA_F);
      ps[r * 4096 + p] = (bf16_t)e;
      lsum[r] += e;
    }
  }
#pragma unroll
  for (int r = 0; r < 8; ++r) atomicAdd(&rs[r], lsum[r]);
  __syncthreads();

  for (int d = tid; d < 768; d += 256) {
    float o[8] = {0, 0, 0, 0, 0, 0, 0, 0};
    for (int p = 0; p < 4096; ++p) {
      const float wv = wc[d * 4096 + p];
#pragma unroll
      for (int r = 0; r < 8; ++r) o[r] += (float)ps[r * 4096 + p] * wv;
    }
#pragma unroll
    for (int r = 0; r < 8; ++r) out[(r0 + r) * 768 + d] = o[r] / rs[r];
  }
}

// ---------------------------------------------------------------- launcher
extern "C" void kernel_launch(void* const* d_in, const int* in_sizes, int n_in,
                              void* d_out, int out_size, void* d_ws, size_t ws_size,
                              hipStream_t stream) {
  (void)in_sizes; (void)n_in; (void)out_size;
  const float* x  = (const float*)d_in[0];
  const float* wl = (const float*)d_in[1];
  const float* wc = (const float*)d_in[2];
  float* out = (float*)d_out;

  const size_t xb_e = (size_t)NTOK * DIM;
  const size_t wl_e = (size_t)NPROT * DIM;
  const size_t wc_e = (size_t)DIM * NPROT;
  const size_t P_e  = (size_t)NTOK * NPROT;
  const size_t need = (xb_e + wl_e + wc_e + P_e) * 2 + (size_t)NTOK * 4;

  if (ws_size >= need) {
    char* ws = (char*)d_ws;
    bf16_t* xb  = (bf16_t*)ws;  ws += xb_e * 2;
    bf16_t* wlb = (bf16_t*)ws;  ws += wl_e * 2;
    bf16_t* wcb = (bf16_t*)ws;  ws += wc_e * 2;
    bf16_t* P   = (bf16_t*)ws;  ws += P_e * 2;
    float* rowsum = (float*)ws;

    hipMemsetAsync(rowsum, 0, NTOK * sizeof(float), stream);
    const int nx8 = (int)(xb_e / 8), nw8 = (int)(wl_e / 8), nc8 = (int)(wc_e / 8);
    cvt_all<<<(nx8 + nw8 + nc8 + 255) / 256, 256, 0, stream>>>(
        x, wl, wc, xb, wlb, wcb, nx8, nw8, nc8);
    // scores+exp+rowsum: M=16384, N=4096, K=768 -> 64x16 = 1024 blocks
    gemm256<0><<<dim3((NTOK / 256) * (NPROT / 256)), 512, 0, stream>>>(
        xb, wlb, (void*)P, rowsum, DIM, NPROT, NPROT / 256);
    // content+normalize: M=16384, N=768, K=4096 -> 64x3 = 192 blocks
    gemm256<1><<<dim3((NTOK / 256) * (DIM / 256)), 512, 0, stream>>>(
        P, wcb, (void*)out, rowsum, NPROT, DIM, DIM / 256);
  } else {
    hopfield_fallback<<<NTOK / 8, 256, 0, stream>>>(x, wl, wc, out);
  }
}

// Round 5
// 429.671 us; speedup vs baseline: 1.2823x; 1.2823x over previous
//
#include <hip/hip_runtime.h>
#include <hip/hip_bf16.h>

// HopfieldLayer: out = softmax(x @ Wl^T * beta) @ Wc^T
//   x [16384,768] f32, Wl [4096,768] f32, Wc [768,4096] f32 -> out [16384,768] f32
// R8: R1's 8-phase 256x256/BK=64 template, de-poisoned per m141: NO
// sched_barrier(0) (order-pinning defeats compiler scheduling), bare
// s_barrier + unclobbered lgkmcnt(0) exactly as the m201 template; optional
// lgkmcnt(8) in 12-read phases. vmcnt(6) at phases 4/8 only (":::memory"
// kept there -- writer-side ledger). Ledger/LDS/epilogues identical to R1.

#define NTOK   16384
#define DIM    768
#define NPROT  4096
#define BETA_F 0.03608439182428583f

typedef __bf16 bf16_t;
typedef __bf16 bf16x8 __attribute__((ext_vector_type(8)));
typedef float  floatx4 __attribute__((ext_vector_type(4)));

// ---------------------------------------------------------------- async 16B copy
__device__ __forceinline__ void async_copy16(const bf16_t* g, void* l) {
  __builtin_amdgcn_global_load_lds(
      (__attribute__((address_space(1))) const void*)g,
      (__attribute__((address_space(3))) void*)l, 16, 0, 0);
}

// ---------------------------------------------------------------- f32 -> bf16
__global__ __launch_bounds__(256) void cvt_all(
    const float* __restrict__ x, const float* __restrict__ wl,
    const float* __restrict__ wc, bf16_t* __restrict__ xb,
    bf16_t* __restrict__ wlb, bf16_t* __restrict__ wcb,
    int nx8, int nw8, int nc8) {
  int i = blockIdx.x * 256 + threadIdx.x;
  const float* in; bf16_t* out; int k;
  if (i < nx8)            { in = x;  out = xb;  k = i; }
  else if (i < nx8 + nw8) { in = wl; out = wlb; k = i - nx8; }
  else if (i < nx8 + nw8 + nc8) { in = wc; out = wcb; k = i - nx8 - nw8; }
  else return;
  const float4* in4 = (const float4*)in;
  float4 a = in4[2 * k], b = in4[2 * k + 1];
  bf16x8 o;
  o[0] = (bf16_t)a.x; o[1] = (bf16_t)a.y; o[2] = (bf16_t)a.z; o[3] = (bf16_t)a.w;
  o[4] = (bf16_t)b.x; o[5] = (bf16_t)b.y; o[6] = (bf16_t)b.z; o[7] = (bf16_t)b.w;
  ((bf16x8*)out)[k] = o;
}

// ---------------------------------------------------------------- gemm C = A * B^T
// 256x256 tile, BK=64, 8 waves 2(M)x4(N). Wave frag rows mfrag=mt*2+wr
// (mt 0..7), cols nfrag=nt*4+wc (nt 0..3). LDS: 32 subfrags of 1KB per
// operand per slot; subfrag (frag,ks): entry l -> row frag*16+(l&15),
// k ks*32+(l>>4)*8. Slots at 0/65536. 8 phases / 2 K-tiles; per phase:
//   { ds_reads ; stage 1 half-tile ; [lgkm(8) if 12 reads] ; s_barrier ;
//     lgkm(0) ; setprio(1) 16 MFMA setprio(0) ; [vmcnt(6) @ p4/p8] ; s_barrier }
template <int EPI>
__global__ __launch_bounds__(512, 2)
void gemm256(const bf16_t* __restrict__ A, const bf16_t* __restrict__ B,
             void* __restrict__ Cv, float* __restrict__ rowsum,
             const int K, const int N, const int nN) {
  __shared__ char lds[131072];

  const int tid = threadIdx.x;
  const int l   = tid & 63;
  const int w   = tid >> 6;       // 0..7
  const int wr  = w >> 2;         // 0..1  (M)
  const int wc  = w & 3;          // 0..3  (N)
  const int lr  = l & 15;
  const int lk  = (l >> 4) << 3;  // 0,8,16,24

  // bijective XCD swizzle (nwg % 8 == 0); n-fast within chunk
  const int nwg   = gridDim.x;
  const int chunk = nwg >> 3;
  const int wg    = (blockIdx.x & 7) * chunk + (blockIdx.x >> 3);
  const int m0    = (wg / nN) * 256;
  const int n0    = (wg % nN) * 256;

  // staging: thread (w,l), j in {0,1} -> subfrag s=j*8+w of a half-tile
  int aoff[2][2], boff[2][2];
#pragma unroll
  for (int h = 0; h < 2; ++h)
#pragma unroll
    for (int j = 0; j < 2; ++j) {
      const int s     = j * 8 + w;
      const int mfrag = h * 8 + (s >> 1);
      const int ks    = s & 1;
      aoff[h][j] = (m0 + mfrag * 16 + lr) * K + ks * 32 + lk;
      boff[h][j] = (n0 + mfrag * 16 + lr) * K + ks * 32 + lk;
    }

  auto stageA = [&](int slot, int kt, int h) {
#pragma unroll
    for (int j = 0; j < 2; ++j) {
      const int s  = j * 8 + w;
      const int sf = (h * 8 + (s >> 1)) * 2 + (s & 1);
      async_copy16(A + aoff[h][j] + kt * 64, lds + slot * 65536 + sf * 1024);
    }
  };
  auto stageB = [&](int slot, int kt, int h) {
#pragma unroll
    for (int j = 0; j < 2; ++j) {
      const int s  = j * 8 + w;
      const int sf = (h * 8 + (s >> 1)) * 2 + (s & 1);
      async_copy16(B + boff[h][j] + kt * 64,
                   lds + slot * 65536 + 32768 + sf * 1024);
    }
  };

  bf16x8 af[4][2], bg[4][2];
  auto loadA = [&](int slot, int mh) {   // af[q] <- mfrag mh*8 + q*2 + wr
#pragma unroll
    for (int q = 0; q < 4; ++q)
#pragma unroll
      for (int ks = 0; ks < 2; ++ks)
        af[q][ks] = *(const bf16x8*)(lds + slot * 65536 +
                        ((mh * 8 + q * 2 + wr) * 2 + ks) * 1024 + l * 16);
  };
  auto loadB = [&](int slot, int nh, int qb) {  // bg[qb+q] <- nfrag nh*8+q*4+wc
#pragma unroll
    for (int q = 0; q < 2; ++q)
#pragma unroll
      for (int ks = 0; ks < 2; ++ks)
        bg[qb + q][ks] = *(const bf16x8*)(lds + slot * 65536 + 32768 +
                        ((nh * 8 + q * 4 + wc) * 2 + ks) * 1024 + l * 16);
  };

  const floatx4 z = {0.f, 0.f, 0.f, 0.f};
  floatx4 acc[8][4];
#pragma unroll
  for (int mt = 0; mt < 8; ++mt)
#pragma unroll
    for (int nt = 0; nt < 4; ++nt) acc[mt][nt] = z;

  auto mma = [&](int mq, int nq) {  // quadrant: mt = mq*4+q, nt = nq*2+r
    __builtin_amdgcn_s_setprio(1);
#pragma unroll
    for (int q = 0; q < 4; ++q)
#pragma unroll
      for (int r = 0; r < 2; ++r)
#pragma unroll
        for (int ks = 0; ks < 2; ++ks)
          acc[mq * 4 + q][nq * 2 + r] = __builtin_amdgcn_mfma_f32_16x16x32_bf16(
              af[q][ks], bg[nq * 2 + r][ks], acc[mq * 4 + q][nq * 2 + r], 0, 0, 0);
    __builtin_amdgcn_s_setprio(0);
  };

#define BAR()    __builtin_amdgcn_s_barrier()
#define LGKM0()  asm volatile("s_waitcnt lgkmcnt(0)")
#define LGKM8()  asm volatile("s_waitcnt lgkmcnt(8)")
#define VM(n)    asm volatile("s_waitcnt vmcnt(" #n ")" ::: "memory")

  const int T = K >> 6;  // K-tiles: 12 (K=768) or 64 (K=4096); both even, >=4

  // prologue: tile0 full (A0,B0,B1,A1) + tile1 {A0,B0,B1}; tile1.A1 at p1 of it 0
  stageA(0, 0, 0); stageB(0, 0, 0); stageB(0, 0, 1); stageA(0, 0, 1);
  stageA(1, 1, 0); stageB(1, 1, 0); stageB(1, 1, 1);
  VM(6);  // tile0 fully landed; tile1's 3 halves remain in flight
  BAR();

#pragma unroll 1
  for (int t = 0; t < T - 2; t += 2) {
    // P1: compute (t, mLo x nLo); stage (t+1).A-h1
    loadA(0, 0); loadB(0, 0, 0);
    stageA(1, t + 1, 1);
    LGKM8();
    BAR(); LGKM0(); mma(0, 0); BAR();
    // P2: (t, mLo x nHi); stage (t+2).A-h0 (slot0 A-h0 died in P1)
    loadB(0, 1, 2);
    stageA(0, t + 2, 0);
    BAR(); LGKM0(); mma(0, 1); BAR();
    // P3: (t, mHi x nHi); stage (t+2).B-h0
    loadA(0, 1);
    stageB(0, t + 2, 0);
    BAR(); LGKM0(); mma(1, 1); BAR();
    // P4: (t, mHi x nLo); stage (t+2).B-h1; vmcnt(6) -> tile t+1 fully landed
    stageB(0, t + 2, 1);
    BAR(); mma(1, 0); VM(6); BAR();
    // P5: compute (t+1, mLo x nLo); stage (t+2).A-h1
    loadA(1, 0); loadB(1, 0, 0);
    stageA(0, t + 2, 1);
    LGKM8();
    BAR(); LGKM0(); mma(0, 0); BAR();
    // P6: (t+1, mLo x nHi); stage (t+3).A-h0
    loadB(1, 1, 2);
    stageA(1, t + 3, 0);
    BAR(); LGKM0(); mma(0, 1); BAR();
    // P7: (t+1, mHi x nHi); stage (t+3).B-h0
    loadA(1, 1);
    stageB(1, t + 3, 0);
    BAR(); LGKM0(); mma(1, 1); BAR();
    // P8: (t+1, mHi x nLo); stage (t+3).B-h1; vmcnt(6) -> tile t+2 fully landed
    stageB(1, t + 3, 1);
    BAR(); mma(1, 0); VM(6); BAR();
  }

  // peeled last pair (t = T-2, T-1): only (T-1).A-h1 left to stage
  loadA(0, 0); loadB(0, 0, 0);
  stageA(1, T - 1, 1);
  LGKM8();
  BAR(); LGKM0(); mma(0, 0); BAR();
  loadB(0, 1, 2);
  BAR(); LGKM0(); mma(0, 1); BAR();
  loadA(0, 1);
  BAR(); LGKM0(); mma(1, 1); BAR();
  BAR(); mma(1, 0); VM(0); BAR();   // drain: (T-1).A-h1 landed
  loadA(1, 0); loadB(1, 0, 0);
  BAR(); LGKM0(); mma(0, 0); BAR();
  loadB(1, 1, 2);
  BAR(); LGKM0(); mma(0, 1); BAR();
  loadA(1, 1);
  BAR(); LGKM0(); mma(1, 1); BAR();
  mma(1, 0);

#undef BAR
#undef LGKM0
#undef LGKM8
#undef VM

  // C/D layout: col = lane&15, row = (lane>>4)*4 + i
  // frag (mt,nt): row = m0+(mt*2+wr)*16+(l>>4)*4+i, col = n0+(nt*4+wc)*16+lr
  const int hi4 = (l >> 4) << 2;
  if (EPI == 0) {
    bf16_t* P = (bf16_t*)Cv;
#pragma unroll
    for (int mt = 0; mt < 8; ++mt) {
      const int row = m0 + (mt * 2 + wr) * 16 + hi4;
      float rs[4] = {0.f, 0.f, 0.f, 0.f};
#pragma unroll
      for (int nt = 0; nt < 4; ++nt) {
        const int col = n0 + (nt * 4 + wc) * 16 + lr;
#pragma unroll
        for (int i = 0; i < 4; ++i) {
          const float e = __expf(acc[mt][nt][i] * BETA_F);
          P[(row + i) * N + col] = (bf16_t)e;
          rs[i] += e;
        }
      }
#pragma unroll
      for (int i = 0; i < 4; ++i) {  // reduce over the 16 col-lanes
        float s = rs[i];
        s += __shfl_xor(s, 1);
        s += __shfl_xor(s, 2);
        s += __shfl_xor(s, 4);
        s += __shfl_xor(s, 8);
        if (lr == 0) atomicAdd(&rowsum[row + i], s);
      }
    }
  } else {
    float* O = (float*)Cv;
#pragma unroll
    for (int mt = 0; mt < 8; ++mt) {
      const int row = m0 + (mt * 2 + wr) * 16 + hi4;
#pragma unroll
      for (int i = 0; i < 4; ++i) {
        const float inv = 1.0f / rowsum[row + i];
#pragma unroll
        for (int nt = 0; nt < 4; ++nt)
          O[(row + i) * N + n0 + (nt * 4 + wc) * 16 + lr] = acc[mt][nt][i] * inv;
      }
    }
  }
}

// ---------------------------------------------------------------- fallback (no ws)
__global__ __launch_bounds__(256) void hopfield_fallback(
    const float* __restrict__ x, const float* __restrict__ wl,
    const float* __restrict__ wc, float* __restrict__ out) {
  __shared__ float  xs[8 * 768];
  __shared__ bf16_t ps[8 * 4096];
  __shared__ float  rs[8];
  const int tid = threadIdx.x;
  const int r0  = blockIdx.x * 8;
  if (tid < 8) rs[tid] = 0.f;
  for (int i = tid; i < 8 * 768; i += 256)
    xs[i] = x[(r0 + (i / 768)) * 768 + (i % 768)];
  __syncthreads();

  float lsum[8] = {0, 0, 0, 0, 0, 0, 0, 0};
  for (int p = tid; p < 4096; p += 256) {
    float s[8] = {0, 0, 0, 0, 0, 0, 0, 0};
    for (int d = 0; d < 768; ++d) {
      const float wv = wl[p * 768 + d];
#pragma unroll
      for (int r = 0; r < 8; ++r) s[r] += xs[r * 768 + d] * wv;
    }
#pragma unroll
    for (int r = 0; r < 8; ++r) {
      const float e = __expf(s[r] * BETA_F);
      ps[r * 4096 + p] = (bf16_t)e;
      lsum[r] += e;
    }
  }
#pragma unroll
  for (int r = 0; r < 8; ++r) atomicAdd(&rs[r], lsum[r]);
  __syncthreads();

  for (int d = tid; d < 768; d += 256) {
    float o[8] = {0, 0, 0, 0, 0, 0, 0, 0};
    for (int p = 0; p < 4096; ++p) {
      const float wv = wc[d * 4096 + p];
#pragma unroll
      for (int r = 0; r < 8; ++r) o[r] += (float)ps[r * 4096 + p] * wv;
    }
#pragma unroll
    for (int r = 0; r < 8; ++r) out[(r0 + r) * 768 + d] = o[r] / rs[r];
  }
}

// ---------------------------------------------------------------- launcher
extern "C" void kernel_launch(void* const* d_in, const int* in_sizes, int n_in,
                              void* d_out, int out_size, void* d_ws, size_t ws_size,
                              hipStream_t stream) {
  (void)in_sizes; (void)n_in; (void)out_size;
  const float* x  = (const float*)d_in[0];
  const float* wl = (const float*)d_in[1];
  const float* wc = (const float*)d_in[2];
  float* out = (float*)d_out;

  const size_t xb_e = (size_t)NTOK * DIM;
  const size_t wl_e = (size_t)NPROT * DIM;
  const size_t wc_e = (size_t)DIM * NPROT;
  const size_t P_e  = (size_t)NTOK * NPROT;
  const size_t need = (xb_e + wl_e + wc_e + P_e) * 2 + (size_t)NTOK * 4;

  if (ws_size >= need) {
    char* ws = (char*)d_ws;
    bf16_t* xb  = (bf16_t*)ws;  ws += xb_e * 2;
    bf16_t* wlb = (bf16_t*)ws;  ws += wl_e * 2;
    bf16_t* wcb = (bf16_t*)ws;  ws += wc_e * 2;
    bf16_t* P   = (bf16_t*)ws;  ws += P_e * 2;
    float* rowsum = (float*)ws;

    hipMemsetAsync(rowsum, 0, NTOK * sizeof(float), stream);
    const int nx8 = (int)(xb_e / 8), nw8 = (int)(wl_e / 8), nc8 = (int)(wc_e / 8);
    cvt_all<<<(nx8 + nw8 + nc8 + 255) / 256, 256, 0, stream>>>(
        x, wl, wc, xb, wlb, wcb, nx8, nw8, nc8);
    // scores+exp+rowsum: M=16384, N=4096, K=768 -> 64x16 = 1024 blocks
    gemm256<0><<<dim3((NTOK / 256) * (NPROT / 256)), 512, 0, stream>>>(
        xb, wlb, (void*)P, rowsum, DIM, NPROT, NPROT / 256);
    // content+normalize: M=16384, N=768, K=4096 -> 64x3 = 192 blocks
    gemm256<1><<<dim3((NTOK / 256) * (DIM / 256)), 512, 0, stream>>>(
        P, wcb, (void*)out, rowsum, NPROT, DIM, DIM / 256);
  } else {
    hopfield_fallback<<<NTOK / 8, 256, 0, stream>>>(x, wl, wc, out);
  }
}